// Round 2
// baseline (307.703 us; speedup 1.0000x reference)
//
#include <hip/hip_runtime.h>
#include <stdint.h>

#define B_ 4
#define T_ 2048
#define D_ 1024
#define H_ 32

typedef unsigned short u16;
typedef __attribute__((ext_vector_type(8))) short bf16x8;
typedef __attribute__((ext_vector_type(4))) float f32x4;

__device__ __forceinline__ u16 f2bf(float f) {
  union { float f; unsigned u; } c; c.f = f;
  unsigned r = 0x7fffu + ((c.u >> 16) & 1u);
  return (u16)((c.u + r) >> 16);
}
__device__ __forceinline__ float bf2f(u16 h) {
  union { unsigned u; float f; } c; c.u = ((unsigned)h) << 16;
  return c.f;
}

__device__ __forceinline__ void gload_lds16(const void* g, void* l) {
  __builtin_amdgcn_global_load_lds(
      (const __attribute__((address_space(1))) void*)g,
      (__attribute__((address_space(3))) void*)l, 16, 0, 0);
}

// ---------------- elementwise f32 -> bf16 cast ----------------
__global__ void cast_f32_to_bf16(const float* __restrict__ in, u16* __restrict__ out, int n4) {
  int idx = blockIdx.x * 256 + threadIdx.x;
  int stride = gridDim.x * 256;
  for (int i = idx; i < n4; i += stride) {
    float4 v = reinterpret_cast<const float4*>(in)[i];
    ushort4 o;
    o.x = f2bf(v.x); o.y = f2bf(v.y); o.z = f2bf(v.z); o.w = f2bf(v.w);
    reinterpret_cast<ushort4*>(out)[i] = o;
  }
}

// ---------------- transpose + cast: out[j][i] = in[i][j] ----------------
__global__ void transpose_cast(const float* __restrict__ in, u16* __restrict__ out, int n) {
  __shared__ float tile[32][33];
  int tx = threadIdx.x & 31, ty = threadIdx.x >> 5;  // 32x8
  int c0 = blockIdx.x * 32, r0 = blockIdx.y * 32;
#pragma unroll
  for (int r = 0; r < 32; r += 8)
    tile[ty + r][tx] = in[(size_t)(r0 + ty + r) * n + c0 + tx];
  __syncthreads();
#pragma unroll
  for (int r = 0; r < 32; r += 8)
    out[(size_t)(c0 + ty + r) * n + r0 + tx] = f2bf(tile[tx][ty + r]);
}

// ---- bias2[d] = sum_j bq[j]*Wk[j][d];  logbias[h] = log(decay[31-h]+1e-10) ----
__global__ void bias2_kernel(const float* __restrict__ bq, const float* __restrict__ Wk,
                             const float* __restrict__ decay,
                             float* __restrict__ out, float* __restrict__ logb) {
  int col = blockIdx.x * 256 + threadIdx.x;
  float acc = 0.f;
  for (int j = 0; j < D_; ++j) acc += bq[j] * Wk[(size_t)j * D_ + col];
  out[col] = acc;
  if (blockIdx.x == 0 && threadIdx.x < H_)
    logb[threadIdx.x] = __logf(decay[H_ - 1 - threadIdx.x] + 1e-10f);
}

// ---------------- bf16 NT GEMM: C[i,j] = sum_k A[i,k]*Bw[j,k] (+bias[j]) (+x[i,j]) ----
// 128x128 tile, BK=32, 256 threads (4 waves, 2x2 of 64x64 each)
template<int OUT_BF16, int ADD_X>
__global__ __launch_bounds__(256, 2)
void gemm_bt(const u16* __restrict__ A, const u16* __restrict__ Bw,
             const float* __restrict__ bias, const float* __restrict__ xadd,
             void* __restrict__ Cv, int M, int N, int K) {
  __shared__ u16 lA[128 * 32];
  __shared__ u16 lB[128 * 32];
  const int tid = threadIdx.x;
  const int bm = blockIdx.x, bn = blockIdx.y;
  const int w = tid >> 6, lane = tid & 63;
  const int wr = w >> 1, wc = w & 1;
  const int lr = lane & 15;
  const int lk = (lane >> 4) << 3;

  f32x4 acc[4][4] = {};

  const int c0 = tid, c1 = tid + 256;
  const size_t aoff0 = (size_t)(bm * 128 + (c0 >> 2)) * K + ((c0 & 3) << 3);
  const size_t aoff1 = (size_t)(bm * 128 + (c1 >> 2)) * K + ((c1 & 3) << 3);
  const size_t boff0 = (size_t)(bn * 128 + (c0 >> 2)) * K + ((c0 & 3) << 3);
  const size_t boff1 = (size_t)(bn * 128 + (c1 >> 2)) * K + ((c1 & 3) << 3);
  u16* lA0 = lA + c0 * 8; u16* lA1 = lA + c1 * 8;
  u16* lB0 = lB + c0 * 8; u16* lB1 = lB + c1 * 8;

  for (int k0 = 0; k0 < K; k0 += 32) {
    gload_lds16(A + aoff0 + k0, lA0);
    gload_lds16(A + aoff1 + k0, lA1);
    gload_lds16(Bw + boff0 + k0, lB0);
    gload_lds16(Bw + boff1 + k0, lB1);
    __syncthreads();
    bf16x8 aF[4], bF[4];
#pragma unroll
    for (int m = 0; m < 4; ++m)
      aF[m] = *reinterpret_cast<const bf16x8*>(&lA[(wr * 64 + m * 16 + lr) * 32 + lk]);
#pragma unroll
    for (int n = 0; n < 4; ++n)
      bF[n] = *reinterpret_cast<const bf16x8*>(&lB[(wc * 64 + n * 16 + lr) * 32 + lk]);
#pragma unroll
    for (int m = 0; m < 4; ++m)
#pragma unroll
      for (int n = 0; n < 4; ++n)
        acc[m][n] = __builtin_amdgcn_mfma_f32_16x16x32_bf16(aF[m], bF[n], acc[m][n], 0, 0, 0);
    __syncthreads();
  }

#pragma unroll
  for (int m = 0; m < 4; ++m) {
    const int row = bm * 128 + wr * 64 + m * 16 + ((lane >> 4) << 2);
#pragma unroll
    for (int n = 0; n < 4; ++n) {
      const int col = bn * 128 + wc * 64 + n * 16 + lr;
      const float bb = bias ? bias[col] : 0.f;
#pragma unroll
      for (int r = 0; r < 4; ++r) {
        float v = acc[m][n][r] + bb;
        if (ADD_X) v += xadd[(size_t)(row + r) * N + col];
        if (OUT_BF16) ((u16*)Cv)[(size_t)(row + r) * N + col] = f2bf(v);
        else          ((float*)Cv)[(size_t)(row + r) * N + col] = v;
      }
    }
  }
}

// ---------------- attention over own-history slice (v2: no LDS staging) -------
// block = one t. Phase 1: wave = batch; lane = (hg in [0,4), dl in [0,16));
// each lane: partial scores for h in {hg*8..hg*8+7} over dims dl*4+64c, c=0..15.
// 16-lane butterfly reduce -> in-register softmax -> p[h][b] table in LDS (512B).
// Phase 2: block-wide; thread owns dims tid*4..+3 for ALL batches; each history
// row read once per block (coalesced 4KB), probs via broadcast ds_read_b128.
__global__ __launch_bounds__(256, 8)
void attn_kernel(const u16* __restrict__ Q2, const float* __restrict__ hist,
                 const float* __restrict__ logb, u16* __restrict__ hw) {
  __shared__ float pTab[H_ * 4];  // [h][b]
  const int t = blockIdx.x;
  const int tid = threadIdx.x;
  const int b = tid >> 6, lane = tid & 63;
  const int hg = lane >> 4, dl = lane & 15;
  const float* hp = hist + (size_t)t * (H_ * D_);
  const u16* qp = Q2 + ((size_t)b * T_ + t) * D_;

  // ---- phase 1: scores ----
  float s[8] = {};
#pragma unroll 4
  for (int c = 0; c < 16; ++c) {
    const int d0 = dl * 4 + 64 * c;
    ushort4 qv = *reinterpret_cast<const ushort4*>(qp + d0);
    float q0 = bf2f(qv.x), q1 = bf2f(qv.y), q2 = bf2f(qv.z), q3 = bf2f(qv.w);
#pragma unroll
    for (int i = 0; i < 8; ++i) {
      float4 hv = *reinterpret_cast<const float4*>(hp + (hg * 8 + i) * D_ + d0);
      s[i] += q0 * hv.x + q1 * hv.y + q2 * hv.z + q3 * hv.w;
    }
  }
  // reduce over the 16 dl-lanes (stays within the hg subgroup)
#pragma unroll
  for (int m = 1; m < 16; m <<= 1)
#pragma unroll
    for (int i = 0; i < 8; ++i) s[i] += __shfl_xor(s[i], m);

  // scale + decay bias
  float mx = -1e30f;
#pragma unroll
  for (int i = 0; i < 8; ++i) {
    s[i] = s[i] * 0.03125f + logb[hg * 8 + i];
    mx = fmaxf(mx, s[i]);
  }
  // global max over all 32 h (4 hg groups)
  mx = fmaxf(mx, __shfl_xor(mx, 16));
  mx = fmaxf(mx, __shfl_xor(mx, 32));
  float lsum = 0.f;
#pragma unroll
  for (int i = 0; i < 8; ++i) { s[i] = __expf(s[i] - mx); lsum += s[i]; }
  lsum += __shfl_xor(lsum, 16);
  lsum += __shfl_xor(lsum, 32);
  const float inv = 1.f / lsum;
  if (dl == 0) {
#pragma unroll
    for (int i = 0; i < 8; ++i) pTab[(hg * 8 + i) * 4 + b] = s[i] * inv;
  }
  __syncthreads();

  // ---- phase 2: weighted history sum, all 4 batches per thread ----
  float acc[4][4] = {};
#pragma unroll 8
  for (int h = 0; h < H_; ++h) {
    float4 hv = *reinterpret_cast<const float4*>(hp + h * D_ + tid * 4);
    f32x4 pv = *reinterpret_cast<const f32x4*>(&pTab[h * 4]);  // broadcast
#pragma unroll
    for (int bb = 0; bb < 4; ++bb) {
      acc[bb][0] += pv[bb] * hv.x;
      acc[bb][1] += pv[bb] * hv.y;
      acc[bb][2] += pv[bb] * hv.z;
      acc[bb][3] += pv[bb] * hv.w;
    }
  }
#pragma unroll
  for (int bb = 0; bb < 4; ++bb) {
    ushort4 o;
    o.x = f2bf(acc[bb][0]); o.y = f2bf(acc[bb][1]);
    o.z = f2bf(acc[bb][2]); o.w = f2bf(acc[bb][3]);
    *reinterpret_cast<ushort4*>(hw + ((size_t)bb * T_ + t) * D_ + tid * 4) = o;
  }
}

extern "C" void kernel_launch(void* const* d_in, const int* in_sizes, int n_in,
                              void* d_out, int out_size, void* d_ws, size_t ws_size,
                              hipStream_t stream) {
  (void)in_sizes; (void)n_in; (void)out_size; (void)ws_size;
  const float* x     = (const float*)d_in[0];
  const float* hist  = (const float*)d_in[1];
  const float* Wq    = (const float*)d_in[2];
  const float* bq    = (const float*)d_in[3];
  const float* Wk    = (const float*)d_in[4];
  // d_in[5] = bk: exactly cancelled by softmax shift-invariance (constant over h)
  const float* Wv    = (const float*)d_in[6];
  const float* bv    = (const float*)d_in[7];
  const float* Wo    = (const float*)d_in[8];
  const float* bo    = (const float*)d_in[9];
  const float* decay = (const float*)d_in[10];

  char* p = (char*)d_ws;
  u16* wqtb = (u16*)p; p += (size_t)D_ * D_ * 2;   // Wq^T bf16
  u16* wktb = (u16*)p; p += (size_t)D_ * D_ * 2;   // Wk^T bf16
  u16* wvb  = (u16*)p; p += (size_t)D_ * D_ * 2;   // Wv bf16
  u16* wob  = (u16*)p; p += (size_t)D_ * D_ * 2;   // Wo bf16
  u16* wqk  = (u16*)p; p += (size_t)D_ * D_ * 2;   // (Wq^T Wk)^T bf16
  float* bias2 = (float*)p; p += 4096;             // bq @ Wk
  float* logb  = (float*)p; p += 4096;             // log(decay[::-1]+1e-10)
  u16* xb   = (u16*)p; p += (size_t)B_ * T_ * D_ * 2;
  u16* Q2b  = (u16*)p; p += (size_t)B_ * T_ * D_ * 2;
  u16* hwb  = (u16*)p; p += (size_t)B_ * T_ * D_ * 2;
  u16* attb = (u16*)p; p += (size_t)B_ * T_ * D_ * 2;

  const int M = B_ * T_;  // 8192

  transpose_cast<<<dim3(32, 32), 256, 0, stream>>>(Wq, wqtb, D_);
  transpose_cast<<<dim3(32, 32), 256, 0, stream>>>(Wk, wktb, D_);
  cast_f32_to_bf16<<<1024, 256, 0, stream>>>(Wv, wvb, D_ * D_ / 4);
  cast_f32_to_bf16<<<1024, 256, 0, stream>>>(Wo, wob, D_ * D_ / 4);
  cast_f32_to_bf16<<<2048, 256, 0, stream>>>(x, xb, M * D_ / 4);
  bias2_kernel<<<D_ / 256, 256, 0, stream>>>(bq, Wk, decay, bias2, logb);

  // Wqk^T[d,a] = sum_j Wk[j,d]*Wq[j,a]
  gemm_bt<1, 0><<<dim3(D_ / 128, D_ / 128), 256, 0, stream>>>(
      wktb, wqtb, nullptr, nullptr, wqk, D_, D_, D_);
  // Q2[i,d] = sum_a x[i,a]*Wqk[a,d] + bias2[d]
  gemm_bt<1, 0><<<dim3(M / 128, D_ / 128), 256, 0, stream>>>(
      xb, wqk, bias2, nullptr, Q2b, M, D_, D_);
  // attention -> hw
  attn_kernel<<<T_, 256, 0, stream>>>(Q2b, hist, logb, hwb);
  // attb = hw @ Wv^T + bv + x
  gemm_bt<1, 1><<<dim3(M / 128, D_ / 128), 256, 0, stream>>>(
      hwb, wvb, bv, x, attb, M, D_, D_);
  // out = attb @ Wo^T + bo  (f32)
  gemm_bt<0, 0><<<dim3(M / 128, D_ / 128), 256, 0, stream>>>(
      attb, wob, bo, nullptr, (float*)d_out, M, D_, D_);
}

// Round 3
// 266.954 us; speedup vs baseline: 1.1526x; 1.1526x over previous
//
#include <hip/hip_runtime.h>
#include <stdint.h>

#define B_ 4
#define T_ 2048
#define D_ 1024
#define H_ 32

typedef unsigned short u16;
typedef __attribute__((ext_vector_type(8))) short bf16x8;
typedef __attribute__((ext_vector_type(4))) float f32x4;

__device__ __forceinline__ u16 f2bf(float f) {
  union { float f; unsigned u; } c; c.f = f;
  unsigned r = 0x7fffu + ((c.u >> 16) & 1u);
  return (u16)((c.u + r) >> 16);
}
__device__ __forceinline__ float bf2f(u16 h) {
  union { unsigned u; float f; } c; c.u = ((unsigned)h) << 16;
  return c.f;
}

__device__ __forceinline__ void gload_lds16(const void* g, void* l) {
  __builtin_amdgcn_global_load_lds(
      (const __attribute__((address_space(1))) void*)g,
      (__attribute__((address_space(3))) void*)l, 16, 0, 0);
}

// ---------------- elementwise f32 -> bf16 cast ----------------
__global__ void cast_f32_to_bf16(const float* __restrict__ in, u16* __restrict__ out, int n4) {
  int idx = blockIdx.x * 256 + threadIdx.x;
  int stride = gridDim.x * 256;
  for (int i = idx; i < n4; i += stride) {
    float4 v = reinterpret_cast<const float4*>(in)[i];
    ushort4 o;
    o.x = f2bf(v.x); o.y = f2bf(v.y); o.z = f2bf(v.z); o.w = f2bf(v.w);
    reinterpret_cast<ushort4*>(out)[i] = o;
  }
}

// ---------------- transpose + cast: out[j][i] = in[i][j] ----------------
__global__ void transpose_cast(const float* __restrict__ in, u16* __restrict__ out, int n) {
  __shared__ float tile[32][33];
  int tx = threadIdx.x & 31, ty = threadIdx.x >> 5;  // 32x8
  int c0 = blockIdx.x * 32, r0 = blockIdx.y * 32;
#pragma unroll
  for (int r = 0; r < 32; r += 8)
    tile[ty + r][tx] = in[(size_t)(r0 + ty + r) * n + c0 + tx];
  __syncthreads();
#pragma unroll
  for (int r = 0; r < 32; r += 8)
    out[(size_t)(c0 + ty + r) * n + r0 + tx] = f2bf(tile[tx][ty + r]);
}

// ---- bias2 = bq @ Wk, two-pass (grid was 4 blocks before: serial tail risk) ----
__global__ void bias2_part(const float* __restrict__ bq, const float* __restrict__ Wk,
                           float* __restrict__ part) {
  int col = blockIdx.x * 256 + threadIdx.x;
  int j0 = blockIdx.y * 64;
  float acc = 0.f;
#pragma unroll 8
  for (int j = 0; j < 64; ++j) acc += bq[j0 + j] * Wk[(size_t)(j0 + j) * D_ + col];
  part[blockIdx.y * D_ + col] = acc;
}
__global__ void bias2_sum(const float* __restrict__ part, const float* __restrict__ decay,
                          float* __restrict__ out, float* __restrict__ logb) {
  int col = blockIdx.x * 256 + threadIdx.x;
  float acc = 0.f;
#pragma unroll
  for (int jb = 0; jb < 16; ++jb) acc += part[jb * D_ + col];
  out[col] = acc;
  if (blockIdx.x == 0 && threadIdx.x < H_)
    logb[threadIdx.x] = __logf(decay[H_ - 1 - threadIdx.x] + 1e-10f);
}

// ---------------- bf16 NT GEMM: C[i,j] = sum_k A[i,k]*Bw[j,k] (+bias[j]) (+x[i,j]) ----
// 128x128 tile, BK=32, 256 threads (4 waves, 2x2 of 64x64 each)
template<int OUT_BF16, int ADD_X>
__global__ __launch_bounds__(256, 2)
void gemm_bt(const u16* __restrict__ A, const u16* __restrict__ Bw,
             const float* __restrict__ bias, const float* __restrict__ xadd,
             void* __restrict__ Cv, int M, int N, int K) {
  __shared__ u16 lA[128 * 32];
  __shared__ u16 lB[128 * 32];
  const int tid = threadIdx.x;
  const int bm = blockIdx.x, bn = blockIdx.y;
  const int w = tid >> 6, lane = tid & 63;
  const int wr = w >> 1, wc = w & 1;
  const int lr = lane & 15;
  const int lk = (lane >> 4) << 3;

  f32x4 acc[4][4] = {};

  const int c0 = tid, c1 = tid + 256;
  const size_t aoff0 = (size_t)(bm * 128 + (c0 >> 2)) * K + ((c0 & 3) << 3);
  const size_t aoff1 = (size_t)(bm * 128 + (c1 >> 2)) * K + ((c1 & 3) << 3);
  const size_t boff0 = (size_t)(bn * 128 + (c0 >> 2)) * K + ((c0 & 3) << 3);
  const size_t boff1 = (size_t)(bn * 128 + (c1 >> 2)) * K + ((c1 & 3) << 3);
  u16* lA0 = lA + c0 * 8; u16* lA1 = lA + c1 * 8;
  u16* lB0 = lB + c0 * 8; u16* lB1 = lB + c1 * 8;

  for (int k0 = 0; k0 < K; k0 += 32) {
    gload_lds16(A + aoff0 + k0, lA0);
    gload_lds16(A + aoff1 + k0, lA1);
    gload_lds16(Bw + boff0 + k0, lB0);
    gload_lds16(Bw + boff1 + k0, lB1);
    __syncthreads();
    bf16x8 aF[4], bF[4];
#pragma unroll
    for (int m = 0; m < 4; ++m)
      aF[m] = *reinterpret_cast<const bf16x8*>(&lA[(wr * 64 + m * 16 + lr) * 32 + lk]);
#pragma unroll
    for (int n = 0; n < 4; ++n)
      bF[n] = *reinterpret_cast<const bf16x8*>(&lB[(wc * 64 + n * 16 + lr) * 32 + lk]);
#pragma unroll
    for (int m = 0; m < 4; ++m)
#pragma unroll
      for (int n = 0; n < 4; ++n)
        acc[m][n] = __builtin_amdgcn_mfma_f32_16x16x32_bf16(aF[m], bF[n], acc[m][n], 0, 0, 0);
    __syncthreads();
  }

#pragma unroll
  for (int m = 0; m < 4; ++m) {
    const int row = bm * 128 + wr * 64 + m * 16 + ((lane >> 4) << 2);
#pragma unroll
    for (int n = 0; n < 4; ++n) {
      const int col = bn * 128 + wc * 64 + n * 16 + lr;
      const float bb = bias ? bias[col] : 0.f;
#pragma unroll
      for (int r = 0; r < 4; ++r) {
        float v = acc[m][n][r] + bb;
        if (ADD_X) v += xadd[(size_t)(row + r) * N + col];
        if (OUT_BF16) ((u16*)Cv)[(size_t)(row + r) * N + col] = f2bf(v);
        else          ((float*)Cv)[(size_t)(row + r) * N + col] = v;
      }
    }
  }
}

// ---------------- attention over own-history slice (v3) ----------------------
// block = one t. Phase 1: wave w owns h-octet [8w,8w+8); lane spans all 1024
// dims via 4 chunks (lane*4 + 256c). Each hist element loaded ONCE per block
// and feeds 4 FMAs (all batches) -> vector-path traffic cut 2.3x vs v2.
// 64-lane butterfly reduce (32 vals), raw scores -> sTab, cheap redundant
// softmax -> pTab, then v2's phase 2 (block-wide weighted sum, hist from L2).
__global__ __launch_bounds__(256, 4)
void attn_kernel(const u16* __restrict__ Q2, const float* __restrict__ hist,
                 const float* __restrict__ logb, u16* __restrict__ hw) {
  __shared__ float sTab[4][H_];  // [b][h] raw scaled+biased scores
  __shared__ float pTab[H_][4];  // [h][b] probabilities
  const int t = blockIdx.x;
  const int tid = threadIdx.x;
  const int w = tid >> 6, lane = tid & 63;
  const float* hp = hist + (size_t)t * (H_ * D_);

  // ---- phase 1: scores for ALL batches, wave covers h in [8w, 8w+8) ----
  float s[32] = {};  // s[b*8+i]
#pragma unroll 2
  for (int c = 0; c < 4; ++c) {
    const int d0 = lane * 4 + 256 * c;
    float qf[4][4];
#pragma unroll
    for (int b = 0; b < 4; ++b) {
      ushort4 qv = *reinterpret_cast<const ushort4*>(Q2 + ((size_t)b * T_ + t) * D_ + d0);
      qf[b][0] = bf2f(qv.x); qf[b][1] = bf2f(qv.y);
      qf[b][2] = bf2f(qv.z); qf[b][3] = bf2f(qv.w);
    }
#pragma unroll
    for (int i = 0; i < 8; ++i) {
      float4 hv = *reinterpret_cast<const float4*>(hp + (w * 8 + i) * D_ + d0);
#pragma unroll
      for (int b = 0; b < 4; ++b)
        s[b * 8 + i] += qf[b][0] * hv.x + qf[b][1] * hv.y +
                        qf[b][2] * hv.z + qf[b][3] * hv.w;
    }
  }
  // butterfly reduce over all 64 lanes
#pragma unroll
  for (int m = 1; m < 64; m <<= 1)
#pragma unroll
    for (int j = 0; j < 32; ++j) s[j] += __shfl_xor(s[j], m);
  if (lane < 32)
    sTab[lane >> 3][w * 8 + (lane & 7)] = s[lane] * 0.03125f + logb[w * 8 + (lane & 7)];
  __syncthreads();

  // ---- softmax: thread (b,h) = (tid>>5, tid&31), redundant m/sum per thread ----
  if (tid < 128) {
    const int b = tid >> 5, h = tid & 31;
    float m0 = -1e30f;
#pragma unroll
    for (int j = 0; j < 32; ++j) m0 = fmaxf(m0, sTab[b][j]);
    float sm = 0.f;
#pragma unroll
    for (int j = 0; j < 32; ++j) sm += __expf(sTab[b][j] - m0);
    pTab[h][b] = __expf(sTab[b][h] - m0) / sm;
  }
  __syncthreads();

  // ---- phase 2: weighted history sum, all 4 batches per thread ----
  float acc[4][4] = {};
#pragma unroll 8
  for (int h = 0; h < H_; ++h) {
    float4 hv = *reinterpret_cast<const float4*>(hp + h * D_ + tid * 4);
    f32x4 pv = *reinterpret_cast<const f32x4*>(&pTab[h][0]);  // broadcast
#pragma unroll
    for (int bb = 0; bb < 4; ++bb) {
      acc[bb][0] += pv[bb] * hv.x;
      acc[bb][1] += pv[bb] * hv.y;
      acc[bb][2] += pv[bb] * hv.z;
      acc[bb][3] += pv[bb] * hv.w;
    }
  }
#pragma unroll
  for (int bb = 0; bb < 4; ++bb) {
    ushort4 o;
    o.x = f2bf(acc[bb][0]); o.y = f2bf(acc[bb][1]);
    o.z = f2bf(acc[bb][2]); o.w = f2bf(acc[bb][3]);
    *reinterpret_cast<ushort4*>(hw + ((size_t)bb * T_ + t) * D_ + tid * 4) = o;
  }
}

extern "C" void kernel_launch(void* const* d_in, const int* in_sizes, int n_in,
                              void* d_out, int out_size, void* d_ws, size_t ws_size,
                              hipStream_t stream) {
  (void)in_sizes; (void)n_in; (void)out_size; (void)ws_size;
  const float* x     = (const float*)d_in[0];
  const float* hist  = (const float*)d_in[1];
  const float* Wq    = (const float*)d_in[2];
  const float* bq    = (const float*)d_in[3];
  const float* Wk    = (const float*)d_in[4];
  // d_in[5] = bk: exactly cancelled by softmax shift-invariance (constant over h)
  const float* Wv    = (const float*)d_in[6];
  const float* bv    = (const float*)d_in[7];
  const float* Wo    = (const float*)d_in[8];
  const float* bo    = (const float*)d_in[9];
  const float* decay = (const float*)d_in[10];

  char* p = (char*)d_ws;
  u16* wqtb = (u16*)p; p += (size_t)D_ * D_ * 2;   // Wq^T bf16
  u16* wktb = (u16*)p; p += (size_t)D_ * D_ * 2;   // Wk^T bf16
  u16* wvb  = (u16*)p; p += (size_t)D_ * D_ * 2;   // Wv bf16
  u16* wob  = (u16*)p; p += (size_t)D_ * D_ * 2;   // Wo bf16
  u16* wqk  = (u16*)p; p += (size_t)D_ * D_ * 2;   // (Wq^T Wk)^T bf16
  float* bias2  = (float*)p; p += 4096;            // bq @ Wk
  float* logb   = (float*)p; p += 4096;            // log(decay[::-1]+1e-10)
  float* b2part = (float*)p; p += 16 * D_ * 4;     // bias2 partials
  u16* xb   = (u16*)p; p += (size_t)B_ * T_ * D_ * 2;
  u16* Q2b  = (u16*)p; p += (size_t)B_ * T_ * D_ * 2;
  u16* hwb  = (u16*)p; p += (size_t)B_ * T_ * D_ * 2;
  u16* attb = (u16*)p; p += (size_t)B_ * T_ * D_ * 2;

  const int M = B_ * T_;  // 8192

  transpose_cast<<<dim3(32, 32), 256, 0, stream>>>(Wq, wqtb, D_);
  transpose_cast<<<dim3(32, 32), 256, 0, stream>>>(Wk, wktb, D_);
  cast_f32_to_bf16<<<1024, 256, 0, stream>>>(Wv, wvb, D_ * D_ / 4);
  cast_f32_to_bf16<<<1024, 256, 0, stream>>>(Wo, wob, D_ * D_ / 4);
  cast_f32_to_bf16<<<2048, 256, 0, stream>>>(x, xb, M * D_ / 4);
  bias2_part<<<dim3(D_ / 256, 16), 256, 0, stream>>>(bq, Wk, b2part);
  bias2_sum<<<D_ / 256, 256, 0, stream>>>(b2part, decay, bias2, logb);

  // Wqk^T[d,a] = sum_j Wk[j,d]*Wq[j,a]
  gemm_bt<1, 0><<<dim3(D_ / 128, D_ / 128), 256, 0, stream>>>(
      wktb, wqtb, nullptr, nullptr, wqk, D_, D_, D_);
  // Q2[i,d] = sum_a x[i,a]*Wqk[a,d] + bias2[d]
  gemm_bt<1, 0><<<dim3(M / 128, D_ / 128), 256, 0, stream>>>(
      xb, wqk, bias2, nullptr, Q2b, M, D_, D_);
  // attention -> hw
  attn_kernel<<<T_, 256, 0, stream>>>(Q2b, hist, logb, hwb);
  // attb = hw @ Wv^T + bv + x
  gemm_bt<1, 1><<<dim3(M / 128, D_ / 128), 256, 0, stream>>>(
      hwb, wvb, bv, x, attb, M, D_, D_);
  // out = attb @ Wo^T + bo  (f32)
  gemm_bt<0, 0><<<dim3(M / 128, D_ / 128), 256, 0, stream>>>(
      attb, wob, bo, nullptr, (float*)d_out, M, D_, D_);
}

// Round 4
// 261.454 us; speedup vs baseline: 1.1769x; 1.0210x over previous
//
#include <hip/hip_runtime.h>
#include <stdint.h>

#define B_ 4
#define T_ 2048
#define D_ 1024
#define H_ 32

typedef unsigned short u16;
typedef __attribute__((ext_vector_type(8))) short bf16x8;
typedef __attribute__((ext_vector_type(4))) float f32x4;

__device__ __forceinline__ u16 f2bf(float f) {
  union { float f; unsigned u; } c; c.f = f;
  unsigned r = 0x7fffu + ((c.u >> 16) & 1u);
  return (u16)((c.u + r) >> 16);
}
__device__ __forceinline__ float bf2f(u16 h) {
  union { unsigned u; float f; } c; c.u = ((unsigned)h) << 16;
  return c.f;
}

__device__ __forceinline__ void gload_lds16(const void* g, void* l) {
  __builtin_amdgcn_global_load_lds(
      (const __attribute__((address_space(1))) void*)g,
      (__attribute__((address_space(3))) void*)l, 16, 0, 0);
}

// ---- weight prep: z=0..2 transpose+cast {Wq,Wk,Wv}; z=3 cast Wo (+copy into Bw2 right half)
__global__ void prep_weights(const float* __restrict__ Wq, const float* __restrict__ Wk,
                             const float* __restrict__ Wv, const float* __restrict__ Wo,
                             u16* __restrict__ wqtb, u16* __restrict__ wktb,
                             u16* __restrict__ wvtb, u16* __restrict__ wob,
                             u16* __restrict__ bw2) {
  const int z = blockIdx.z;
  const int tx = threadIdx.x & 31, ty = threadIdx.x >> 5;  // 32x8
  const int c0 = blockIdx.x * 32, r0 = blockIdx.y * 32;
  if (z == 3) {
#pragma unroll
    for (int r = 0; r < 32; r += 8) {
      const int row = r0 + ty + r, col = c0 + tx;
      const u16 v = f2bf(Wo[(size_t)row * D_ + col]);
      wob[(size_t)row * D_ + col] = v;
      bw2[(size_t)row * 2048 + 1024 + col] = v;
    }
    return;
  }
  const float* in = (z == 0) ? Wq : (z == 1) ? Wk : Wv;
  u16* out = (z == 0) ? wqtb : (z == 1) ? wktb : wvtb;
  __shared__ float tile[32][33];
#pragma unroll
  for (int r = 0; r < 32; r += 8)
    tile[ty + r][tx] = in[(size_t)(r0 + ty + r) * D_ + c0 + tx];
  __syncthreads();
#pragma unroll
  for (int r = 0; r < 32; r += 8)
    out[(size_t)(c0 + ty + r) * D_ + r0 + tx] = f2bf(tile[tx][ty + r]);
}

// ---- cast x -> bf16 into right half of concat panel A2 [8192][2048] ----
__global__ void cast_x_to_A2(const float* __restrict__ x, u16* __restrict__ A2) {
  int i4 = blockIdx.x * 256 + threadIdx.x;
  const int stride = gridDim.x * 256;
  for (; i4 < (B_ * T_ * D_) / 4; i4 += stride) {
    const int row = i4 >> 8, c4 = i4 & 255;  // D/4 = 256
    float4 v = reinterpret_cast<const float4*>(x)[i4];
    ushort4 o;
    o.x = f2bf(v.x); o.y = f2bf(v.y); o.z = f2bf(v.z); o.w = f2bf(v.w);
    *reinterpret_cast<ushort4*>(A2 + (size_t)row * 2048 + 1024 + c4 * 4) = o;
  }
}

// ---- bias2 = bq @ Wk (two-pass) ; logb ----
__global__ void bias2_part(const float* __restrict__ bq, const float* __restrict__ Wk,
                           float* __restrict__ part) {
  int col = blockIdx.x * 256 + threadIdx.x;
  int j0 = blockIdx.y * 64;
  float acc = 0.f;
#pragma unroll 8
  for (int j = 0; j < 64; ++j) acc += bq[j0 + j] * Wk[(size_t)(j0 + j) * D_ + col];
  part[blockIdx.y * D_ + col] = acc;
}
__global__ void bias2_sum(const float* __restrict__ part, const float* __restrict__ decay,
                          float* __restrict__ out, float* __restrict__ logb) {
  int col = blockIdx.x * 256 + threadIdx.x;
  float acc = 0.f;
#pragma unroll
  for (int jb = 0; jb < 16; ++jb) acc += part[jb * D_ + col];
  out[col] = acc;
  if (blockIdx.x == 0 && threadIdx.x < H_)
    logb[threadIdx.x] = __logf(decay[H_ - 1 - threadIdx.x] + 1e-10f);
}

// ---- bvo[j] = sum_k bv[k]*Wo[j,k] + bo[j] (wave per row j) ----
__global__ void bvo_kernel(const float* __restrict__ bv, const float* __restrict__ Wo,
                           const float* __restrict__ bo, float* __restrict__ bvo) {
  const int wid = threadIdx.x >> 6, lane = threadIdx.x & 63;
  const int j = blockIdx.x * 4 + wid;
  float acc = 0.f;
#pragma unroll
  for (int k4 = lane; k4 < 256; k4 += 64) {
    float4 w = *reinterpret_cast<const float4*>(Wo + (size_t)j * D_ + k4 * 4);
    float4 b = *reinterpret_cast<const float4*>(bv + k4 * 4);
    acc += w.x * b.x + w.y * b.y + w.z * b.z + w.w * b.w;
  }
#pragma unroll
  for (int m = 1; m < 64; m <<= 1) acc += __shfl_xor(acc, m);
  if (lane == 0) bvo[j] = acc + bo[j];
}

// ---- reduce 4 split-K f32 partial slabs [4][D][D] -> bf16 out (row stride ostride) ----
__global__ void reduce4_cast(const float* __restrict__ part, u16* __restrict__ out, int ostride) {
  const int i4 = blockIdx.x * 256 + threadIdx.x;  // over D*D/4
  const int row = i4 >> 8, c4 = i4 & 255;
  const size_t slab = (size_t)D_ * D_;
  const size_t base = (size_t)row * D_ + c4 * 4;
  float4 a = *reinterpret_cast<const float4*>(part + base);
  float4 b = *reinterpret_cast<const float4*>(part + slab + base);
  float4 c = *reinterpret_cast<const float4*>(part + 2 * slab + base);
  float4 d = *reinterpret_cast<const float4*>(part + 3 * slab + base);
  ushort4 o;
  o.x = f2bf(a.x + b.x + c.x + d.x);
  o.y = f2bf(a.y + b.y + c.y + d.y);
  o.z = f2bf(a.z + b.z + c.z + d.z);
  o.w = f2bf(a.w + b.w + c.w + d.w);
  *reinterpret_cast<ushort4*>(out + (size_t)row * ostride + c4 * 4) = o;
}

// ---------------- bf16 NT GEMM: C[i,j] = sum_k A[i,k]*Bw[j,k] (+bias[j]) ----
// 128x128 tile, BK=32, 256 threads (4 waves, 2x2 of 64x64 each).
// lda/ldb/ldc in elements. SPLITK: blockIdx.z selects k-slab of length K,
// writes f32 partial at Cv + z*M*ldc (no bias).
template<int OUT_BF16, int SPLITK>
__global__ __launch_bounds__(256, 2)
void gemm_bt(const u16* __restrict__ A, const u16* __restrict__ Bw,
             const float* __restrict__ bias, void* __restrict__ Cv,
             int M, int N, int K, int lda, int ldb, int ldc) {
  __shared__ u16 lA[128 * 32];
  __shared__ u16 lB[128 * 32];
  if (SPLITK) {
    A += (size_t)blockIdx.z * K;
    Bw += (size_t)blockIdx.z * K;
    Cv = (float*)Cv + (size_t)blockIdx.z * M * ldc;
  }
  const int tid = threadIdx.x;
  const int bm = blockIdx.x, bn = blockIdx.y;
  const int w = tid >> 6, lane = tid & 63;
  const int wr = w >> 1, wc = w & 1;
  const int lr = lane & 15;
  const int lk = (lane >> 4) << 3;

  f32x4 acc[4][4] = {};

  const int c0 = tid, c1 = tid + 256;
  const size_t aoff0 = (size_t)(bm * 128 + (c0 >> 2)) * lda + ((c0 & 3) << 3);
  const size_t aoff1 = (size_t)(bm * 128 + (c1 >> 2)) * lda + ((c1 & 3) << 3);
  const size_t boff0 = (size_t)(bn * 128 + (c0 >> 2)) * ldb + ((c0 & 3) << 3);
  const size_t boff1 = (size_t)(bn * 128 + (c1 >> 2)) * ldb + ((c1 & 3) << 3);
  u16* lA0 = lA + c0 * 8; u16* lA1 = lA + c1 * 8;
  u16* lB0 = lB + c0 * 8; u16* lB1 = lB + c1 * 8;

  for (int k0 = 0; k0 < K; k0 += 32) {
    gload_lds16(A + aoff0 + k0, lA0);
    gload_lds16(A + aoff1 + k0, lA1);
    gload_lds16(Bw + boff0 + k0, lB0);
    gload_lds16(Bw + boff1 + k0, lB1);
    __syncthreads();
    bf16x8 aF[4], bF[4];
#pragma unroll
    for (int m = 0; m < 4; ++m)
      aF[m] = *reinterpret_cast<const bf16x8*>(&lA[(wr * 64 + m * 16 + lr) * 32 + lk]);
#pragma unroll
    for (int n = 0; n < 4; ++n)
      bF[n] = *reinterpret_cast<const bf16x8*>(&lB[(wc * 64 + n * 16 + lr) * 32 + lk]);
#pragma unroll
    for (int m = 0; m < 4; ++m)
#pragma unroll
      for (int n = 0; n < 4; ++n)
        acc[m][n] = __builtin_amdgcn_mfma_f32_16x16x32_bf16(aF[m], bF[n], acc[m][n], 0, 0, 0);
    __syncthreads();
  }

#pragma unroll
  for (int m = 0; m < 4; ++m) {
    const int row = bm * 128 + wr * 64 + m * 16 + ((lane >> 4) << 2);
#pragma unroll
    for (int n = 0; n < 4; ++n) {
      const int col = bn * 128 + wc * 64 + n * 16 + lr;
      const float bb = (!SPLITK && bias) ? bias[col] : 0.f;
#pragma unroll
      for (int r = 0; r < 4; ++r) {
        float v = acc[m][n][r] + bb;
        if (OUT_BF16) ((u16*)Cv)[(size_t)(row + r) * ldc + col] = f2bf(v);
        else          ((float*)Cv)[(size_t)(row + r) * ldc + col] = v;
      }
    }
  }
}

// ---------------- attention over own-history slice (v3) ----------------------
// block = one t. Phase 1: wave w owns h-octet; lane spans all 1024 dims.
// Each hist element loaded once per block, feeds all 4 batches.
// Output hw written into LEFT half of concat panel A2 (row stride 2048).
__global__ __launch_bounds__(256, 4)
void attn_kernel(const u16* __restrict__ Q2, const float* __restrict__ hist,
                 const float* __restrict__ logb, u16* __restrict__ A2) {
  __shared__ float sTab[4][H_];
  __shared__ float pTab[H_][4];
  const int t = blockIdx.x;
  const int tid = threadIdx.x;
  const int w = tid >> 6, lane = tid & 63;
  const float* hp = hist + (size_t)t * (H_ * D_);

  float s[32] = {};
#pragma unroll 2
  for (int c = 0; c < 4; ++c) {
    const int d0 = lane * 4 + 256 * c;
    float qf[4][4];
#pragma unroll
    for (int b = 0; b < 4; ++b) {
      ushort4 qv = *reinterpret_cast<const ushort4*>(Q2 + ((size_t)b * T_ + t) * D_ + d0);
      qf[b][0] = bf2f(qv.x); qf[b][1] = bf2f(qv.y);
      qf[b][2] = bf2f(qv.z); qf[b][3] = bf2f(qv.w);
    }
#pragma unroll
    for (int i = 0; i < 8; ++i) {
      float4 hv = *reinterpret_cast<const float4*>(hp + (w * 8 + i) * D_ + d0);
#pragma unroll
      for (int b = 0; b < 4; ++b)
        s[b * 8 + i] += qf[b][0] * hv.x + qf[b][1] * hv.y +
                        qf[b][2] * hv.z + qf[b][3] * hv.w;
    }
  }
#pragma unroll
  for (int m = 1; m < 64; m <<= 1)
#pragma unroll
    for (int j = 0; j < 32; ++j) s[j] += __shfl_xor(s[j], m);
  if (lane < 32)
    sTab[lane >> 3][w * 8 + (lane & 7)] = s[lane] * 0.03125f + logb[w * 8 + (lane & 7)];
  __syncthreads();

  if (tid < 128) {
    const int b = tid >> 5, h = tid & 31;
    float m0 = -1e30f;
#pragma unroll
    for (int j = 0; j < 32; ++j) m0 = fmaxf(m0, sTab[b][j]);
    float sm = 0.f;
#pragma unroll
    for (int j = 0; j < 32; ++j) sm += __expf(sTab[b][j] - m0);
    pTab[h][b] = __expf(sTab[b][h] - m0) / sm;
  }
  __syncthreads();

  float acc[4][4] = {};
#pragma unroll 8
  for (int h = 0; h < H_; ++h) {
    float4 hv = *reinterpret_cast<const float4*>(hp + h * D_ + tid * 4);
    f32x4 pv = *reinterpret_cast<const f32x4*>(&pTab[h][0]);
#pragma unroll
    for (int bb = 0; bb < 4; ++bb) {
      acc[bb][0] += pv[bb] * hv.x;
      acc[bb][1] += pv[bb] * hv.y;
      acc[bb][2] += pv[bb] * hv.z;
      acc[bb][3] += pv[bb] * hv.w;
    }
  }
#pragma unroll
  for (int bb = 0; bb < 4; ++bb) {
    ushort4 o;
    o.x = f2bf(acc[bb][0]); o.y = f2bf(acc[bb][1]);
    o.z = f2bf(acc[bb][2]); o.w = f2bf(acc[bb][3]);
    *reinterpret_cast<ushort4*>(A2 + ((size_t)bb * T_ + t) * 2048 + tid * 4) = o;
  }
}

extern "C" void kernel_launch(void* const* d_in, const int* in_sizes, int n_in,
                              void* d_out, int out_size, void* d_ws, size_t ws_size,
                              hipStream_t stream) {
  (void)in_sizes; (void)n_in; (void)out_size; (void)ws_size;
  const float* x     = (const float*)d_in[0];
  const float* hist  = (const float*)d_in[1];
  const float* Wq    = (const float*)d_in[2];
  const float* bq    = (const float*)d_in[3];
  const float* Wk    = (const float*)d_in[4];
  // d_in[5] = bk: exactly cancelled by softmax shift-invariance
  const float* Wv    = (const float*)d_in[6];
  const float* bv    = (const float*)d_in[7];
  const float* Wo    = (const float*)d_in[8];
  const float* bo    = (const float*)d_in[9];
  const float* decay = (const float*)d_in[10];

  char* p = (char*)d_ws;
  u16* wqtb = (u16*)p; p += (size_t)D_ * D_ * 2;      // Wq^T bf16
  u16* wktb = (u16*)p; p += (size_t)D_ * D_ * 2;      // Wk^T bf16
  u16* wvtb = (u16*)p; p += (size_t)D_ * D_ * 2;      // Wv^T bf16
  u16* wob  = (u16*)p; p += (size_t)D_ * D_ * 2;      // Wo bf16
  u16* wqk  = (u16*)p; p += (size_t)D_ * D_ * 2;      // (Wq^T Wk)^T bf16
  u16* bw2  = (u16*)p; p += (size_t)D_ * 2048 * 2;    // [Wvo | Wo] bf16, ldb=2048
  float* bias2  = (float*)p; p += 4096;               // bq @ Wk
  float* logb   = (float*)p; p += 4096;
  float* bvo    = (float*)p; p += 4096;               // bv @ Wo^T + bo
  float* b2part = (float*)p; p += 16 * D_ * 4;
  float* pk     = (float*)p; p += (size_t)4 * D_ * D_ * 4;  // split-K partials (16MB)
  u16* A2   = (u16*)p; p += (size_t)B_ * T_ * 2048 * 2;     // [hw | x] bf16, lda=2048
  u16* Q2b  = (u16*)p; p += (size_t)B_ * T_ * D_ * 2;

  const int M = B_ * T_;  // 8192

  prep_weights<<<dim3(32, 32, 4), 256, 0, stream>>>(Wq, Wk, Wv, Wo, wqtb, wktb, wvtb, wob, bw2);
  cast_x_to_A2<<<2048, 256, 0, stream>>>(x, A2);
  bias2_part<<<dim3(D_ / 256, 16), 256, 0, stream>>>(bq, Wk, b2part);
  bias2_sum<<<D_ / 256, 256, 0, stream>>>(b2part, decay, bias2, logb);
  bvo_kernel<<<D_ / 4, 256, 0, stream>>>(bv, Wo, bo, bvo);

  // Wqk^T[d,a] = sum_j Wk[j,d]*Wq[j,a]  (split-K=4 -> f32 partials -> bf16)
  gemm_bt<0, 1><<<dim3(8, 8, 4), 256, 0, stream>>>(
      wktb, wqtb, nullptr, pk, D_, D_, D_ / 4, D_, D_, D_);
  reduce4_cast<<<1024, 256, 0, stream>>>(pk, wqk, D_);
  // Wvo[j,k] = sum_a Wo[j,a]*Wv[a,k] -> left half of bw2 (split-K=4)
  gemm_bt<0, 1><<<dim3(8, 8, 4), 256, 0, stream>>>(
      wob, wvtb, nullptr, pk, D_, D_, D_ / 4, D_, D_, D_);
  reduce4_cast<<<1024, 256, 0, stream>>>(pk, bw2, 2048);
  // Q2[i,d] = sum_a x[i,a]*Wqk[a,d] + bias2[d]   (A = right half of A2)
  gemm_bt<1, 0><<<dim3(M / 128, D_ / 128), 256, 0, stream>>>(
      A2 + 1024, wqk, bias2, Q2b, M, D_, D_, 2048, D_, D_);
  // attention -> hw (left half of A2)
  attn_kernel<<<T_, 256, 0, stream>>>(Q2b, hist, logb, A2);
  // out[i,j] = sum_{k<2048} A2[i,k]*bw2[j,k] + bvo[j]   == (attended+x)@Wo^T+bo
  gemm_bt<0, 0><<<dim3(M / 128, D_ / 128), 256, 0, stream>>>(
      A2, bw2, bvo, (float*)d_out, M, D_, 2048, 2048, 2048, D_);
}

// Round 5
// 242.188 us; speedup vs baseline: 1.2705x; 1.0796x over previous
//
#include <hip/hip_runtime.h>
#include <stdint.h>

#define B_ 4
#define T_ 2048
#define D_ 1024
#define H_ 32

typedef unsigned short u16;
typedef __attribute__((ext_vector_type(8))) short bf16x8;
typedef __attribute__((ext_vector_type(4))) float f32x4;

__device__ __forceinline__ u16 f2bf(float f) {
  union { float f; unsigned u; } c; c.f = f;
  unsigned r = 0x7fffu + ((c.u >> 16) & 1u);
  return (u16)((c.u + r) >> 16);
}
__device__ __forceinline__ float bf2f(u16 h) {
  union { unsigned u; float f; } c; c.u = ((unsigned)h) << 16;
  return c.f;
}

__device__ __forceinline__ void gload_lds16(const void* g, void* l) {
  __builtin_amdgcn_global_load_lds(
      (const __attribute__((address_space(1))) void*)g,
      (__attribute__((address_space(3))) void*)l, 16, 0, 0);
}

// ---- weight prep: z=0..2 transpose+cast {Wq,Wk,Wv}; z=3 cast Wo -> wob AND b2w bottom half
__global__ void prep_weights(const float* __restrict__ Wq, const float* __restrict__ Wk,
                             const float* __restrict__ Wv, const float* __restrict__ Wo,
                             u16* __restrict__ wqtb, u16* __restrict__ wktb,
                             u16* __restrict__ wvtb, u16* __restrict__ wob,
                             u16* __restrict__ b2w) {
  const int z = blockIdx.z;
  const int tx = threadIdx.x & 31, ty = threadIdx.x >> 5;  // 32x8
  const int c0 = blockIdx.x * 32, r0 = blockIdx.y * 32;
  if (z == 3) {
#pragma unroll
    for (int r = 0; r < 32; r += 8) {
      const int row = r0 + ty + r, col = c0 + tx;
      const u16 v = f2bf(Wo[(size_t)row * D_ + col]);
      wob[(size_t)row * D_ + col] = v;
      b2w[(size_t)(D_ + row) * D_ + col] = v;  // xo-part rows of concat B
    }
    return;
  }
  const float* in = (z == 0) ? Wq : (z == 1) ? Wk : Wv;
  u16* out = (z == 0) ? wqtb : (z == 1) ? wktb : wvtb;
  __shared__ float tile[32][33];
#pragma unroll
  for (int r = 0; r < 32; r += 8)
    tile[ty + r][tx] = in[(size_t)(r0 + ty + r) * D_ + c0 + tx];
  __syncthreads();
#pragma unroll
  for (int r = 0; r < 32; r += 8)
    out[(size_t)(c0 + ty + r) * D_ + r0 + tx] = f2bf(tile[tx][ty + r]);
}

// ---- cast x -> bf16 xb [8192][1024] ----
__global__ void cast_x(const float* __restrict__ x, u16* __restrict__ xb) {
  int i4 = blockIdx.x * 256 + threadIdx.x;
  const int stride = gridDim.x * 256;
  for (; i4 < (B_ * T_ * D_) / 4; i4 += stride) {
    float4 v = reinterpret_cast<const float4*>(x)[i4];
    ushort4 o;
    o.x = f2bf(v.x); o.y = f2bf(v.y); o.z = f2bf(v.z); o.w = f2bf(v.w);
    *reinterpret_cast<ushort4*>(xb + (size_t)i4 * 4) = o;
  }
}

// ---- bias2 = bq @ Wk (two-pass); upper half of extended bias = 0; logb ----
__global__ void bias2_part(const float* __restrict__ bq, const float* __restrict__ Wk,
                           float* __restrict__ part) {
  int col = blockIdx.x * 256 + threadIdx.x;
  int j0 = blockIdx.y * 64;
  float acc = 0.f;
#pragma unroll 8
  for (int j = 0; j < 64; ++j) acc += bq[j0 + j] * Wk[(size_t)(j0 + j) * D_ + col];
  part[blockIdx.y * D_ + col] = acc;
}
__global__ void bias2_sum(const float* __restrict__ part, const float* __restrict__ decay,
                          float* __restrict__ out, float* __restrict__ logb) {
  int col = blockIdx.x * 256 + threadIdx.x;
  float acc = 0.f;
#pragma unroll
  for (int jb = 0; jb < 16; ++jb) acc += part[jb * D_ + col];
  out[col] = acc;
  out[D_ + col] = 0.f;  // xo columns get no bias in GEMM1
  if (blockIdx.x == 0 && threadIdx.x < H_)
    logb[threadIdx.x] = __logf(decay[H_ - 1 - threadIdx.x] + 1e-10f);
}

// ---- bvo[j] = sum_k bv[k]*Wo[j,k] + bo[j] (wave per row j) ----
__global__ void bvo_kernel(const float* __restrict__ bv, const float* __restrict__ Wo,
                           const float* __restrict__ bo, float* __restrict__ bvo) {
  const int wid = threadIdx.x >> 6, lane = threadIdx.x & 63;
  const int j = blockIdx.x * 4 + wid;
  float acc = 0.f;
#pragma unroll
  for (int k4 = lane; k4 < 256; k4 += 64) {
    float4 w = *reinterpret_cast<const float4*>(Wo + (size_t)j * D_ + k4 * 4);
    float4 b = *reinterpret_cast<const float4*>(bv + k4 * 4);
    acc += w.x * b.x + w.y * b.y + w.z * b.z + w.w * b.w;
  }
#pragma unroll
  for (int m = 1; m < 64; m <<= 1) acc += __shfl_xor(acc, m);
  if (lane == 0) bvo[j] = acc + bo[j];
}

// ---- reduce split-K partials: blocks<1024 -> b2w top (Wqk); else -> wvo ----
__global__ void reduce8_cast(const float* __restrict__ part, u16* __restrict__ b2w,
                             u16* __restrict__ wvo) {
  const int tgt = blockIdx.x >> 10;
  const int i4 = (blockIdx.x & 1023) * 256 + threadIdx.x;  // over D*D/4
  const int row = i4 >> 8, c4 = i4 & 255;
  const size_t slab = (size_t)D_ * D_;
  const size_t base = (size_t)tgt * 4 * slab + (size_t)row * D_ + c4 * 4;
  float4 a = *reinterpret_cast<const float4*>(part + base);
  float4 b = *reinterpret_cast<const float4*>(part + slab + base);
  float4 c = *reinterpret_cast<const float4*>(part + 2 * slab + base);
  float4 d = *reinterpret_cast<const float4*>(part + 3 * slab + base);
  ushort4 o;
  o.x = f2bf(a.x + b.x + c.x + d.x);
  o.y = f2bf(a.y + b.y + c.y + d.y);
  o.z = f2bf(a.z + b.z + c.z + d.z);
  o.w = f2bf(a.w + b.w + c.w + d.w);
  u16* out = tgt ? wvo : b2w;
  *reinterpret_cast<ushort4*>(out + (size_t)row * D_ + c4 * 4) = o;
}

// ---------------- bf16 NT GEMM core: C[i,j] = sum_k A[i,k]*Bw[j,k] (+bias[j]) (+xadd[i,j]) ----
// 128x128 tile, BK=32, 256 threads (4 waves, 2x2 of 64x64 each).
template<int OUT_BF16, int ADDX>
__device__ __forceinline__ void gemm_core(
    const u16* __restrict__ A, const u16* __restrict__ Bw,
    const float* __restrict__ bias, const u16* __restrict__ xadd, int ldx,
    void* __restrict__ Cv, int K, int lda, int ldb, int ldc, int bm, int bn) {
  __shared__ u16 lA[128 * 32];
  __shared__ u16 lB[128 * 32];
  const int tid = threadIdx.x;
  const int w = tid >> 6, lane = tid & 63;
  const int wr = w >> 1, wc = w & 1;
  const int lr = lane & 15;
  const int lk = (lane >> 4) << 3;

  f32x4 acc[4][4] = {};

  const int c0 = tid, c1 = tid + 256;
  const size_t aoff0 = (size_t)(bm * 128 + (c0 >> 2)) * lda + ((c0 & 3) << 3);
  const size_t aoff1 = (size_t)(bm * 128 + (c1 >> 2)) * lda + ((c1 & 3) << 3);
  const size_t boff0 = (size_t)(bn * 128 + (c0 >> 2)) * ldb + ((c0 & 3) << 3);
  const size_t boff1 = (size_t)(bn * 128 + (c1 >> 2)) * ldb + ((c1 & 3) << 3);
  u16* lA0 = lA + c0 * 8; u16* lA1 = lA + c1 * 8;
  u16* lB0 = lB + c0 * 8; u16* lB1 = lB + c1 * 8;

  for (int k0 = 0; k0 < K; k0 += 32) {
    gload_lds16(A + aoff0 + k0, lA0);
    gload_lds16(A + aoff1 + k0, lA1);
    gload_lds16(Bw + boff0 + k0, lB0);
    gload_lds16(Bw + boff1 + k0, lB1);
    __syncthreads();
    bf16x8 aF[4], bF[4];
#pragma unroll
    for (int m = 0; m < 4; ++m)
      aF[m] = *reinterpret_cast<const bf16x8*>(&lA[(wr * 64 + m * 16 + lr) * 32 + lk]);
#pragma unroll
    for (int n = 0; n < 4; ++n)
      bF[n] = *reinterpret_cast<const bf16x8*>(&lB[(wc * 64 + n * 16 + lr) * 32 + lk]);
#pragma unroll
    for (int m = 0; m < 4; ++m)
#pragma unroll
      for (int n = 0; n < 4; ++n)
        acc[m][n] = __builtin_amdgcn_mfma_f32_16x16x32_bf16(aF[m], bF[n], acc[m][n], 0, 0, 0);
    __syncthreads();
  }

#pragma unroll
  for (int m = 0; m < 4; ++m) {
    const int row = bm * 128 + wr * 64 + m * 16 + ((lane >> 4) << 2);
#pragma unroll
    for (int n = 0; n < 4; ++n) {
      const int col = bn * 128 + wc * 64 + n * 16 + lr;
      const float bb = bias ? bias[col] : 0.f;
#pragma unroll
      for (int r = 0; r < 4; ++r) {
        float v = acc[m][n][r] + bb;
        if (ADDX) v += bf2f(xadd[(size_t)(row + r) * ldx + col]);
        if (OUT_BF16) ((u16*)Cv)[(size_t)(row + r) * ldc + col] = f2bf(v);
        else          ((float*)Cv)[(size_t)(row + r) * ldc + col] = v;
      }
    }
  }
}

template<int OUT_BF16, int ADDX>
__global__ __launch_bounds__(256, 2)
void gemm_bt(const u16* __restrict__ A, const u16* __restrict__ Bw,
             const float* __restrict__ bias, const u16* __restrict__ xadd, int ldx,
             void* __restrict__ Cv, int K, int lda, int ldb, int ldc) {
  gemm_core<OUT_BF16, ADDX>(A, Bw, bias, xadd, ldx, Cv, K, lda, ldb, ldc,
                            blockIdx.x, blockIdx.y);
}

// ---- both 1024^3 weight GEMMs in one launch: z<4 -> Wqk slabs, z>=4 -> Wvo slabs ----
__global__ __launch_bounds__(256, 2)
void gemm_splitk_dual(const u16* __restrict__ wktb, const u16* __restrict__ wqtb,
                      const u16* __restrict__ wob, const u16* __restrict__ wvtb,
                      float* __restrict__ pk) {
  const int z = blockIdx.z;
  const u16 *A, *B;
  if (z < 4) { A = wktb + z * 256; B = wqtb + z * 256; }
  else       { A = wob + (z - 4) * 256; B = wvtb + (z - 4) * 256; }
  float* C = pk + (size_t)z * D_ * D_;
  gemm_core<0, 0>(A, B, nullptr, nullptr, 0, C, 256, D_, D_, D_,
                  blockIdx.x, blockIdx.y);
}

// ---------------- attention over own-history slice (v3) ----------------------
// block = one t. Phase 1: wave w owns h-octet; lane spans all 1024 dims.
// Each hist element loaded once per block, feeds all 4 batches.
__global__ __launch_bounds__(256, 4)
void attn_kernel(const u16* __restrict__ Q2, const float* __restrict__ hist,
                 const float* __restrict__ logb, u16* __restrict__ hw) {
  __shared__ float sTab[4][H_];
  __shared__ float pTab[H_][4];
  const int t = blockIdx.x;
  const int tid = threadIdx.x;
  const int w = tid >> 6, lane = tid & 63;
  const float* hp = hist + (size_t)t * (H_ * D_);

  float s[32] = {};
#pragma unroll 2
  for (int c = 0; c < 4; ++c) {
    const int d0 = lane * 4 + 256 * c;
    float qf[4][4];
#pragma unroll
    for (int b = 0; b < 4; ++b) {
      ushort4 qv = *reinterpret_cast<const ushort4*>(Q2 + ((size_t)b * T_ + t) * 2048 + d0);
      qf[b][0] = bf2f(qv.x); qf[b][1] = bf2f(qv.y);
      qf[b][2] = bf2f(qv.z); qf[b][3] = bf2f(qv.w);
    }
#pragma unroll
    for (int i = 0; i < 8; ++i) {
      float4 hv = *reinterpret_cast<const float4*>(hp + (w * 8 + i) * D_ + d0);
#pragma unroll
      for (int b = 0; b < 4; ++b)
        s[b * 8 + i] += qf[b][0] * hv.x + qf[b][1] * hv.y +
                        qf[b][2] * hv.z + qf[b][3] * hv.w;
    }
  }
#pragma unroll
  for (int m = 1; m < 64; m <<= 1)
#pragma unroll
    for (int j = 0; j < 32; ++j) s[j] += __shfl_xor(s[j], m);
  if (lane < 32)
    sTab[lane >> 3][w * 8 + (lane & 7)] = s[lane] * 0.03125f + logb[w * 8 + (lane & 7)];
  __syncthreads();

  if (tid < 128) {
    const int b = tid >> 5, h = tid & 31;
    float m0 = -1e30f;
#pragma unroll
    for (int j = 0; j < 32; ++j) m0 = fmaxf(m0, sTab[b][j]);
    float sm = 0.f;
#pragma unroll
    for (int j = 0; j < 32; ++j) sm += __expf(sTab[b][j] - m0);
    pTab[h][b] = __expf(sTab[b][h] - m0) / sm;
  }
  __syncthreads();

  float acc[4][4] = {};
#pragma unroll 8
  for (int h = 0; h < H_; ++h) {
    float4 hv = *reinterpret_cast<const float4*>(hp + h * D_ + tid * 4);
    f32x4 pv = *reinterpret_cast<const f32x4*>(&pTab[h][0]);
#pragma unroll
    for (int bb = 0; bb < 4; ++bb) {
      acc[bb][0] += pv[bb] * hv.x;
      acc[bb][1] += pv[bb] * hv.y;
      acc[bb][2] += pv[bb] * hv.z;
      acc[bb][3] += pv[bb] * hv.w;
    }
  }
#pragma unroll
  for (int bb = 0; bb < 4; ++bb) {
    ushort4 o;
    o.x = f2bf(acc[bb][0]); o.y = f2bf(acc[bb][1]);
    o.z = f2bf(acc[bb][2]); o.w = f2bf(acc[bb][3]);
    *reinterpret_cast<ushort4*>(hw + ((size_t)bb * T_ + t) * D_ + tid * 4) = o;
  }
}

extern "C" void kernel_launch(void* const* d_in, const int* in_sizes, int n_in,
                              void* d_out, int out_size, void* d_ws, size_t ws_size,
                              hipStream_t stream) {
  (void)in_sizes; (void)n_in; (void)out_size; (void)ws_size;
  const float* x     = (const float*)d_in[0];
  const float* hist  = (const float*)d_in[1];
  const float* Wq    = (const float*)d_in[2];
  const float* bq    = (const float*)d_in[3];
  const float* Wk    = (const float*)d_in[4];
  // d_in[5] = bk: exactly cancelled by softmax shift-invariance
  const float* Wv    = (const float*)d_in[6];
  const float* bv    = (const float*)d_in[7];
  const float* Wo    = (const float*)d_in[8];
  const float* bo    = (const float*)d_in[9];
  const float* decay = (const float*)d_in[10];

  char* p = (char*)d_ws;
  u16* wqtb = (u16*)p; p += (size_t)D_ * D_ * 2;      // Wq^T bf16
  u16* wktb = (u16*)p; p += (size_t)D_ * D_ * 2;      // Wk^T bf16
  u16* wvtb = (u16*)p; p += (size_t)D_ * D_ * 2;      // Wv^T bf16
  u16* wob  = (u16*)p; p += (size_t)D_ * D_ * 2;      // Wo bf16
  u16* wvo  = (u16*)p; p += (size_t)D_ * D_ * 2;      // Wo@Wv bf16
  u16* b2w  = (u16*)p; p += (size_t)2 * D_ * D_ * 2;  // [Wqk ; Wo] rows, ldb=1024
  float* bias2  = (float*)p; p += 2 * D_ * 4;         // [bq@Wk | zeros]
  float* logb   = (float*)p; p += 4096;
  float* bvo    = (float*)p; p += 4096;               // bv@Wo^T + bo
  float* b2part = (float*)p; p += 16 * D_ * 4;
  float* pk     = (float*)p; p += (size_t)8 * D_ * D_ * 4;  // split-K partials (32MB)
  u16* xb   = (u16*)p; p += (size_t)B_ * T_ * D_ * 2;       // x bf16
  u16* Q2b  = (u16*)p; p += (size_t)B_ * T_ * 2048 * 2;     // [Q2 | xo] bf16, ldc=2048
  u16* hwb  = (u16*)p; p += (size_t)B_ * T_ * D_ * 2;       // attn output bf16

  const int M = B_ * T_;  // 8192

  prep_weights<<<dim3(32, 32, 4), 256, 0, stream>>>(Wq, Wk, Wv, Wo, wqtb, wktb, wvtb, wob, b2w);
  cast_x<<<2048, 256, 0, stream>>>(x, xb);
  bias2_part<<<dim3(D_ / 256, 16), 256, 0, stream>>>(bq, Wk, b2part);
  bias2_sum<<<D_ / 256, 256, 0, stream>>>(b2part, decay, bias2, logb);
  bvo_kernel<<<D_ / 4, 256, 0, stream>>>(bv, Wo, bo, bvo);

  // Wqk (slabs 0..3) and Wvo (slabs 4..7) in one 512-block launch
  gemm_splitk_dual<<<dim3(8, 8, 8), 256, 0, stream>>>(wktb, wqtb, wob, wvtb, pk);
  reduce8_cast<<<2048, 256, 0, stream>>>(pk, b2w, wvo);

  // GEMM1: [Q2 | xo] = xb @ b2w^T + [bias2 | 0]   (M=8192, N=2048, K=1024 -> 1024 blocks)
  gemm_bt<1, 0><<<dim3(M / 128, 2048 / 128), 256, 0, stream>>>(
      xb, b2w, bias2, nullptr, 0, Q2b, D_, D_, D_, 2048);
  // attention -> hw
  attn_kernel<<<T_, 256, 0, stream>>>(Q2b, hist, logb, hwb);
  // out = hw @ wvo^T + xo + bvo   (f32 out)
  gemm_bt<0, 1><<<dim3(M / 128, D_ / 128), 256, 0, stream>>>(
      hwb, wvo, bvo, Q2b + 1024, 2048, (float*)d_out, D_, D_, D_, D_);
}

// Round 6
// 186.197 us; speedup vs baseline: 1.6526x; 1.3007x over previous
//
#include <hip/hip_runtime.h>
#include <stdint.h>

#define B_ 4
#define T_ 2048
#define D_ 1024
#define H_ 32

typedef unsigned short u16;
typedef __attribute__((ext_vector_type(8))) short bf16x8;
typedef __attribute__((ext_vector_type(4))) float f32x4;

__device__ __forceinline__ u16 f2bf(float f) {
  union { float f; unsigned u; } c; c.f = f;
  unsigned r = 0x7fffu + ((c.u >> 16) & 1u);
  return (u16)((c.u + r) >> 16);
}
__device__ __forceinline__ float bf2f(u16 h) {
  union { unsigned u; float f; } c; c.u = ((unsigned)h) << 16;
  return c.f;
}

__device__ __forceinline__ void gload_lds16(const void* g, void* l) {
  __builtin_amdgcn_global_load_lds(
      (const __attribute__((address_space(1))) void*)g,
      (__attribute__((address_space(3))) void*)l, 16, 0, 0);
}

// ================= megaprep: all independent prep work, one launch ==========
// blocks [0,4096): weight transpose/cast (z = bid>>10: 0=Wq,1=Wk,2=Wv,3=Wo)
// blocks [4096,6144): cast x -> bf16 xb
// blocks [6144,6208): bias2 partials (bq @ Wk)
// blocks [6208,6464): bvo[j] = bv @ Wo^T + bo
__global__ void megaprep(const float* __restrict__ x,
                         const float* __restrict__ Wq, const float* __restrict__ Wk,
                         const float* __restrict__ Wv, const float* __restrict__ Wo,
                         const float* __restrict__ bq, const float* __restrict__ bv,
                         const float* __restrict__ bo,
                         u16* __restrict__ xb,
                         u16* __restrict__ wqtb, u16* __restrict__ wktb,
                         u16* __restrict__ wvtb, u16* __restrict__ wob,
                         u16* __restrict__ b2w,
                         float* __restrict__ b2part, float* __restrict__ bvo) {
  const int bid = blockIdx.x;
  const int tid = threadIdx.x;
  if (bid < 4096) {
    const int z = bid >> 10, tile = bid & 1023;
    const int tx = tid & 31, ty = tid >> 5;  // 32x8
    const int c0 = (tile & 31) * 32, r0 = (tile >> 5) * 32;
    if (z == 3) {
#pragma unroll
      for (int r = 0; r < 32; r += 8) {
        const int row = r0 + ty + r, col = c0 + tx;
        const u16 v = f2bf(Wo[(size_t)row * D_ + col]);
        wob[(size_t)row * D_ + col] = v;
        b2w[(size_t)(D_ + row) * D_ + col] = v;  // xo-part rows of concat B
      }
      return;
    }
    const float* in = (z == 0) ? Wq : (z == 1) ? Wk : Wv;
    u16* out = (z == 0) ? wqtb : (z == 1) ? wktb : wvtb;
    __shared__ float tile_s[32][33];
#pragma unroll
    for (int r = 0; r < 32; r += 8)
      tile_s[ty + r][tx] = in[(size_t)(r0 + ty + r) * D_ + c0 + tx];
    __syncthreads();
#pragma unroll
    for (int r = 0; r < 32; r += 8)
      out[(size_t)(c0 + ty + r) * D_ + r0 + tx] = f2bf(tile_s[tx][ty + r]);
  } else if (bid < 6144) {
    const int base = (bid - 4096) * 1024;
#pragma unroll
    for (int k = 0; k < 4; ++k) {
      const int i4 = base + k * 256 + tid;
      float4 v = reinterpret_cast<const float4*>(x)[i4];
      ushort4 o;
      o.x = f2bf(v.x); o.y = f2bf(v.y); o.z = f2bf(v.z); o.w = f2bf(v.w);
      *reinterpret_cast<ushort4*>(xb + (size_t)i4 * 4) = o;
    }
  } else if (bid < 6208) {
    const int sub = bid - 6144;
    const int col = (sub & 3) * 256 + tid;
    const int j0 = (sub >> 2) * 64;
    float acc = 0.f;
#pragma unroll 8
    for (int j = 0; j < 64; ++j) acc += bq[j0 + j] * Wk[(size_t)(j0 + j) * D_ + col];
    b2part[(sub >> 2) * D_ + col] = acc;
  } else {
    const int wid = tid >> 6, lane = tid & 63;
    const int j = (bid - 6208) * 4 + wid;
    float acc = 0.f;
#pragma unroll
    for (int k4 = lane; k4 < 256; k4 += 64) {
      float4 w = *reinterpret_cast<const float4*>(Wo + (size_t)j * D_ + k4 * 4);
      float4 b = *reinterpret_cast<const float4*>(bv + k4 * 4);
      acc += w.x * b.x + w.y * b.y + w.z * b.z + w.w * b.w;
    }
#pragma unroll
    for (int m = 1; m < 64; m <<= 1) acc += __shfl_xor(acc, m);
    if (lane == 0) bvo[j] = acc + bo[j];
  }
}

// ====== finish: reduce split-K partials + finalize bias2 + logb, one launch ==
// blocks [0,2048): reduce pk slabs -> b2w top (Wqk) / wvo
// blocks [2048,2052): bias2 = sum(b2part), zero upper half; block 2048: logb
__global__ void finish_kernel(const float* __restrict__ pk, const float* __restrict__ b2part,
                              const float* __restrict__ decay,
                              u16* __restrict__ b2w, u16* __restrict__ wvo,
                              float* __restrict__ bias2, float* __restrict__ logb) {
  const int bid = blockIdx.x;
  const int tid = threadIdx.x;
  if (bid < 2048) {
    const int tgt = bid >> 10;
    const int i4 = (bid & 1023) * 256 + tid;
    const int row = i4 >> 8, c4 = i4 & 255;
    const size_t slab = (size_t)D_ * D_;
    const size_t base = (size_t)tgt * 4 * slab + (size_t)row * D_ + c4 * 4;
    float4 a = *reinterpret_cast<const float4*>(pk + base);
    float4 b = *reinterpret_cast<const float4*>(pk + slab + base);
    float4 c = *reinterpret_cast<const float4*>(pk + 2 * slab + base);
    float4 d = *reinterpret_cast<const float4*>(pk + 3 * slab + base);
    ushort4 o;
    o.x = f2bf(a.x + b.x + c.x + d.x);
    o.y = f2bf(a.y + b.y + c.y + d.y);
    o.z = f2bf(a.z + b.z + c.z + d.z);
    o.w = f2bf(a.w + b.w + c.w + d.w);
    u16* out = tgt ? wvo : b2w;
    *reinterpret_cast<ushort4*>(out + (size_t)row * D_ + c4 * 4) = o;
  } else {
    const int col = (bid - 2048) * 256 + tid;
    float acc = 0.f;
#pragma unroll
    for (int jb = 0; jb < 16; ++jb) acc += b2part[jb * D_ + col];
    bias2[col] = acc;
    bias2[D_ + col] = 0.f;
    if (bid == 2048 && tid < H_)
      logb[tid] = __logf(decay[H_ - 1 - tid] + 1e-10f);
  }
}

// ---------------- bf16 NT GEMM core: C[i,j] = sum_k A[i,k]*Bw[j,k] (+bias[j]) (+xadd[i,j]) ----
// 128x128 tile, BK=32, 256 threads (4 waves, 2x2 of 64x64 each).
template<int OUT_BF16, int ADDX>
__device__ __forceinline__ void gemm_core(
    const u16* __restrict__ A, const u16* __restrict__ Bw,
    const float* __restrict__ bias, const u16* __restrict__ xadd, int ldx,
    void* __restrict__ Cv, int K, int lda, int ldb, int ldc, int bm, int bn) {
  __shared__ u16 lA[128 * 32];
  __shared__ u16 lB[128 * 32];
  const int tid = threadIdx.x;
  const int w = tid >> 6, lane = tid & 63;
  const int wr = w >> 1, wc = w & 1;
  const int lr = lane & 15;
  const int lk = (lane >> 4) << 3;

  f32x4 acc[4][4] = {};

  const int c0 = tid, c1 = tid + 256;
  const size_t aoff0 = (size_t)(bm * 128 + (c0 >> 2)) * lda + ((c0 & 3) << 3);
  const size_t aoff1 = (size_t)(bm * 128 + (c1 >> 2)) * lda + ((c1 & 3) << 3);
  const size_t boff0 = (size_t)(bn * 128 + (c0 >> 2)) * ldb + ((c0 & 3) << 3);
  const size_t boff1 = (size_t)(bn * 128 + (c1 >> 2)) * ldb + ((c1 & 3) << 3);
  u16* lA0 = lA + c0 * 8; u16* lA1 = lA + c1 * 8;
  u16* lB0 = lB + c0 * 8; u16* lB1 = lB + c1 * 8;

  for (int k0 = 0; k0 < K; k0 += 32) {
    gload_lds16(A + aoff0 + k0, lA0);
    gload_lds16(A + aoff1 + k0, lA1);
    gload_lds16(Bw + boff0 + k0, lB0);
    gload_lds16(Bw + boff1 + k0, lB1);
    __syncthreads();
    bf16x8 aF[4], bF[4];
#pragma unroll
    for (int m = 0; m < 4; ++m)
      aF[m] = *reinterpret_cast<const bf16x8*>(&lA[(wr * 64 + m * 16 + lr) * 32 + lk]);
#pragma unroll
    for (int n = 0; n < 4; ++n)
      bF[n] = *reinterpret_cast<const bf16x8*>(&lB[(wc * 64 + n * 16 + lr) * 32 + lk]);
#pragma unroll
    for (int m = 0; m < 4; ++m)
#pragma unroll
      for (int n = 0; n < 4; ++n)
        acc[m][n] = __builtin_amdgcn_mfma_f32_16x16x32_bf16(aF[m], bF[n], acc[m][n], 0, 0, 0);
    __syncthreads();
  }

#pragma unroll
  for (int m = 0; m < 4; ++m) {
    const int row = bm * 128 + wr * 64 + m * 16 + ((lane >> 4) << 2);
#pragma unroll
    for (int n = 0; n < 4; ++n) {
      const int col = bn * 128 + wc * 64 + n * 16 + lr;
      const float bb = bias ? bias[col] : 0.f;
#pragma unroll
      for (int r = 0; r < 4; ++r) {
        float v = acc[m][n][r] + bb;
        if (ADDX) v += bf2f(xadd[(size_t)(row + r) * ldx + col]);
        if (OUT_BF16) ((u16*)Cv)[(size_t)(row + r) * ldc + col] = f2bf(v);
        else          ((float*)Cv)[(size_t)(row + r) * ldc + col] = v;
      }
    }
  }
}

template<int OUT_BF16, int ADDX>
__global__ __launch_bounds__(256, 2)
void gemm_bt(const u16* __restrict__ A, const u16* __restrict__ Bw,
             const float* __restrict__ bias, const u16* __restrict__ xadd, int ldx,
             void* __restrict__ Cv, int K, int lda, int ldb, int ldc) {
  gemm_core<OUT_BF16, ADDX>(A, Bw, bias, xadd, ldx, Cv, K, lda, ldb, ldc,
                            blockIdx.x, blockIdx.y);
}

// ---- both 1024^3 weight GEMMs in one launch: z<4 -> Wqk slabs, z>=4 -> Wvo slabs ----
__global__ __launch_bounds__(256, 2)
void gemm_splitk_dual(const u16* __restrict__ wktb, const u16* __restrict__ wqtb,
                      const u16* __restrict__ wob, const u16* __restrict__ wvtb,
                      float* __restrict__ pk) {
  const int z = blockIdx.z;
  const u16 *A, *B;
  if (z < 4) { A = wktb + z * 256; B = wqtb + z * 256; }
  else       { A = wob + (z - 4) * 256; B = wvtb + (z - 4) * 256; }
  float* C = pk + (size_t)z * D_ * D_;
  gemm_core<0, 0>(A, B, nullptr, nullptr, 0, C, 256, D_, D_, D_,
                  blockIdx.x, blockIdx.y);
}

// ---------------- attention over own-history slice (v5) ----------------------
// block = one t. Phase 1 reads each hist element ONCE from global (f32),
// computes scores AND stashes bf16 copy to LDS. Phase 2 reads LDS only.
// Per-block global vector traffic: 136KB (was 264KB) -> HBM-bound (~48us floor).
__global__ __launch_bounds__(256, 2)
void attn_kernel(const u16* __restrict__ Q2, const float* __restrict__ hist,
                 const float* __restrict__ logb, u16* __restrict__ hw) {
  __shared__ u16 lh[H_ * D_];    // 64KB bf16 [h][d]
  __shared__ float sTab[4][H_];
  __shared__ float pTab[H_][4];
  const int t = blockIdx.x;
  const int tid = threadIdx.x;
  const int w = tid >> 6, lane = tid & 63;
  const float* hp = hist + (size_t)t * (H_ * D_);

  // ---- phase 1: scores for ALL batches; wave w covers h in [8w, 8w+8) ----
  float s[32] = {};  // s[b*8+i]
#pragma unroll 2
  for (int c = 0; c < 4; ++c) {
    const int d0 = lane * 4 + 256 * c;
    float qf[4][4];
#pragma unroll
    for (int b = 0; b < 4; ++b) {
      ushort4 qv = *reinterpret_cast<const ushort4*>(Q2 + ((size_t)b * T_ + t) * 2048 + d0);
      qf[b][0] = bf2f(qv.x); qf[b][1] = bf2f(qv.y);
      qf[b][2] = bf2f(qv.z); qf[b][3] = bf2f(qv.w);
    }
#pragma unroll
    for (int i = 0; i < 8; ++i) {
      const int h = w * 8 + i;
      float4 hv = *reinterpret_cast<const float4*>(hp + h * D_ + d0);
      ushort4 hb;
      hb.x = f2bf(hv.x); hb.y = f2bf(hv.y); hb.z = f2bf(hv.z); hb.w = f2bf(hv.w);
      *reinterpret_cast<ushort4*>(&lh[h * D_ + d0]) = hb;  // stash for phase 2
#pragma unroll
      for (int b = 0; b < 4; ++b)
        s[b * 8 + i] += qf[b][0] * hv.x + qf[b][1] * hv.y +
                        qf[b][2] * hv.z + qf[b][3] * hv.w;
    }
  }
#pragma unroll
  for (int m = 1; m < 64; m <<= 1)
#pragma unroll
    for (int j = 0; j < 32; ++j) s[j] += __shfl_xor(s[j], m);
  if (lane < 32)
    sTab[lane >> 3][w * 8 + (lane & 7)] = s[lane] * 0.03125f + logb[w * 8 + (lane & 7)];
  __syncthreads();  // also covers the lh ds_writes

  if (tid < 128) {
    const int b = tid >> 5, h = tid & 31;
    float m0 = -1e30f;
#pragma unroll
    for (int j = 0; j < 32; ++j) m0 = fmaxf(m0, sTab[b][j]);
    float sm = 0.f;
#pragma unroll
    for (int j = 0; j < 32; ++j) sm += __expf(sTab[b][j] - m0);
    pTab[h][b] = __expf(sTab[b][h] - m0) / sm;
  }
  __syncthreads();

  // ---- phase 2: weighted sum from LDS (bf16), all 4 batches per thread ----
  float acc[4][4] = {};
#pragma unroll 8
  for (int h = 0; h < H_; ++h) {
    ushort4 hv = *reinterpret_cast<const ushort4*>(&lh[h * D_ + tid * 4]);
    const float h0 = bf2f(hv.x), h1 = bf2f(hv.y), h2 = bf2f(hv.z), h3 = bf2f(hv.w);
    f32x4 pv = *reinterpret_cast<const f32x4*>(&pTab[h][0]);
#pragma unroll
    for (int bb = 0; bb < 4; ++bb) {
      acc[bb][0] += pv[bb] * h0;
      acc[bb][1] += pv[bb] * h1;
      acc[bb][2] += pv[bb] * h2;
      acc[bb][3] += pv[bb] * h3;
    }
  }
#pragma unroll
  for (int bb = 0; bb < 4; ++bb) {
    ushort4 o;
    o.x = f2bf(acc[bb][0]); o.y = f2bf(acc[bb][1]);
    o.z = f2bf(acc[bb][2]); o.w = f2bf(acc[bb][3]);
    *reinterpret_cast<ushort4*>(hw + ((size_t)bb * T_ + t) * D_ + tid * 4) = o;
  }
}

extern "C" void kernel_launch(void* const* d_in, const int* in_sizes, int n_in,
                              void* d_out, int out_size, void* d_ws, size_t ws_size,
                              hipStream_t stream) {
  (void)in_sizes; (void)n_in; (void)out_size; (void)ws_size;
  const float* x     = (const float*)d_in[0];
  const float* hist  = (const float*)d_in[1];
  const float* Wq    = (const float*)d_in[2];
  const float* bq    = (const float*)d_in[3];
  const float* Wk    = (const float*)d_in[4];
  // d_in[5] = bk: exactly cancelled by softmax shift-invariance
  const float* Wv    = (const float*)d_in[6];
  const float* bv    = (const float*)d_in[7];
  const float* Wo    = (const float*)d_in[8];
  const float* bo    = (const float*)d_in[9];
  const float* decay = (const float*)d_in[10];

  char* p = (char*)d_ws;
  u16* wqtb = (u16*)p; p += (size_t)D_ * D_ * 2;      // Wq^T bf16
  u16* wktb = (u16*)p; p += (size_t)D_ * D_ * 2;      // Wk^T bf16
  u16* wvtb = (u16*)p; p += (size_t)D_ * D_ * 2;      // Wv^T bf16
  u16* wob  = (u16*)p; p += (size_t)D_ * D_ * 2;      // Wo bf16
  u16* wvo  = (u16*)p; p += (size_t)D_ * D_ * 2;      // Wo@Wv bf16
  u16* b2w  = (u16*)p; p += (size_t)2 * D_ * D_ * 2;  // [Wqk ; Wo] rows, ldb=1024
  float* bias2  = (float*)p; p += 2 * D_ * 4;         // [bq@Wk | zeros]
  float* logb   = (float*)p; p += 4096;
  float* bvo    = (float*)p; p += 4096;               // bv@Wo^T + bo
  float* b2part = (float*)p; p += 16 * D_ * 4;
  float* pk     = (float*)p; p += (size_t)8 * D_ * D_ * 4;  // split-K partials (32MB)
  u16* xb   = (u16*)p; p += (size_t)B_ * T_ * D_ * 2;       // x bf16
  u16* Q2b  = (u16*)p; p += (size_t)B_ * T_ * 2048 * 2;     // [Q2 | xo] bf16, ldc=2048
  u16* hwb  = (u16*)p; p += (size_t)B_ * T_ * D_ * 2;       // attn output bf16

  const int M = B_ * T_;  // 8192

  megaprep<<<6464, 256, 0, stream>>>(x, Wq, Wk, Wv, Wo, bq, bv, bo,
                                     xb, wqtb, wktb, wvtb, wob, b2w, b2part, bvo);
  gemm_splitk_dual<<<dim3(8, 8, 8), 256, 0, stream>>>(wktb, wqtb, wob, wvtb, pk);
  finish_kernel<<<2052, 256, 0, stream>>>(pk, b2part, decay, b2w, wvo, bias2, logb);

  // GEMM1: [Q2 | xo] = xb @ b2w^T + [bias2 | 0]   (M=8192, N=2048, K=1024)
  gemm_bt<1, 0><<<dim3(M / 128, 2048 / 128), 256, 0, stream>>>(
      xb, b2w, bias2, nullptr, 0, Q2b, D_, D_, D_, 2048);
  // attention -> hw
  attn_kernel<<<T_, 256, 0, stream>>>(Q2b, hist, logb, hwb);
  // out = hw @ wvo^T + xo + bvo   (f32 out)
  gemm_bt<0, 1><<<dim3(M / 128, D_ / 128), 256, 0, stream>>>(
      hwb, wvo, bvo, Q2b + 1024, 2048, (float*)d_out, D_, D_, D_, D_);
}